// Round 2
// baseline (1711.824 us; speedup 1.0000x reference)
//
#include <hip/hip_runtime.h>
#include <math.h>

typedef __attribute__((ext_vector_type(4))) float f32x4;
typedef __attribute__((ext_vector_type(8))) __bf16 bf16x8;
typedef __attribute__((ext_vector_type(4))) unsigned short us4;

__device__ __forceinline__ unsigned short f2bf(float f) {
  unsigned int u = __float_as_uint(f);
  u += 0x7fffu + ((u >> 16) & 1u);            // RNE
  return (unsigned short)(u >> 16);
}
__device__ __forceinline__ float bf2f(unsigned short h) {
  return __uint_as_float(((unsigned int)h) << 16);
}

__device__ __forceinline__ void gload16(const void* g, void* l) {
  __builtin_amdgcn_global_load_lds(
      (__attribute__((address_space(1))) void*)g,
      (__attribute__((address_space(3))) void*)l, 16, 0, 0);
}

// ---------------- fp32 -> bf16 convert (plain) ----------------
__global__ __launch_bounds__(256) void cvt_bf16(const float* __restrict__ in,
                                                unsigned short* __restrict__ out, int n4) {
  int i = blockIdx.x * 256 + threadIdx.x;
  if (i < n4) {
    float4 v = ((const float4*)in)[i];
    us4 o;
    o[0] = f2bf(v.x); o[1] = f2bf(v.y); o[2] = f2bf(v.z); o[3] = f2bf(v.w);
    ((us4*)out)[i] = o;
  }
}

// ---------------- fp32 -> (hi, lo) bf16 split ----------------
__global__ __launch_bounds__(256) void cvt_split(const float* __restrict__ in,
                                                 unsigned short* __restrict__ hi,
                                                 unsigned short* __restrict__ lo, int n4) {
  int i = blockIdx.x * 256 + threadIdx.x;
  if (i < n4) {
    float4 v = ((const float4*)in)[i];
    us4 h, l;
    float vv[4] = {v.x, v.y, v.z, v.w};
#pragma unroll
    for (int j = 0; j < 4; ++j) {
      unsigned short hh = f2bf(vv[j]);
      h[j] = hh;
      l[j] = f2bf(vv[j] - bf2f(hh));
    }
    ((us4*)hi)[i] = h;
    ((us4*)lo)[i] = l;
  }
}

// ---------------- GEMM: C = A * B^T (bf16 in, fp32 acc) ----------------
// SM: 0 = bf16 row-major C, 1 = bf16 C^T (C[n][m]), 2 = fp32 row-major store, 3 = fp32 accumulate (+=)
template<int SM>
__global__ __launch_bounds__(256) void gemm_bt(const unsigned short* __restrict__ A,
                                               const unsigned short* __restrict__ B,
                                               void* __restrict__ C,
                                               int M, int N, int K) {
  __shared__ __align__(16) unsigned short As[128 * 32];
  __shared__ __align__(16) unsigned short Bs[128 * 32];
  const int tid = threadIdx.x;
  const int w = tid >> 6, l = tid & 63;
  const int wm = w >> 1, wn = w & 1;
  const int lr = l & 15, lg = l >> 4;
  const long m0 = (long)blockIdx.y * 128, n0 = (long)blockIdx.x * 128;

  f32x4 acc[4][4] = {};

  const int c0 = w * 128 + l;
  const int c1 = c0 + 64;
  const unsigned short* gA0 = A + (m0 + (c0 >> 2)) * K + (c0 & 3) * 8;
  const unsigned short* gA1 = A + (m0 + (c1 >> 2)) * K + (c1 & 3) * 8;
  const unsigned short* gB0 = B + (n0 + (c0 >> 2)) * K + (c0 & 3) * 8;
  const unsigned short* gB1 = B + (n0 + (c1 >> 2)) * K + (c1 & 3) * 8;

  for (int kt = 0; kt < K; kt += 32) {
    gload16(gA0 + kt, &As[(w * 128) * 8]);
    gload16(gA1 + kt, &As[(w * 128 + 64) * 8]);
    gload16(gB0 + kt, &Bs[(w * 128) * 8]);
    gload16(gB1 + kt, &Bs[(w * 128 + 64) * 8]);
    __syncthreads();
    bf16x8 af[4], bfr[4];
#pragma unroll
    for (int mi = 0; mi < 4; ++mi)
      af[mi] = *(const bf16x8*)&As[(wm * 64 + mi * 16 + lr) * 32 + lg * 8];
#pragma unroll
    for (int ni = 0; ni < 4; ++ni)
      bfr[ni] = *(const bf16x8*)&Bs[(wn * 64 + ni * 16 + lr) * 32 + lg * 8];
#pragma unroll
    for (int mi = 0; mi < 4; ++mi)
#pragma unroll
      for (int ni = 0; ni < 4; ++ni)
        acc[mi][ni] = __builtin_amdgcn_mfma_f32_16x16x32_bf16(af[mi], bfr[ni], acc[mi][ni], 0, 0, 0);
    __syncthreads();
  }

#pragma unroll
  for (int mi = 0; mi < 4; ++mi)
#pragma unroll
    for (int ni = 0; ni < 4; ++ni)
#pragma unroll
      for (int j = 0; j < 4; ++j) {
        long r = m0 + wm * 64 + mi * 16 + lg * 4 + j;
        long cc = n0 + wn * 64 + ni * 16 + lr;
        float v = acc[mi][ni][j];
        if (SM == 0)      ((unsigned short*)C)[r * N + cc] = f2bf(v);
        else if (SM == 1) ((unsigned short*)C)[cc * M + r] = f2bf(v);
        else if (SM == 2) ((float*)C)[r * N + cc] = v;
        else              ((float*)C)[r * N + cc] += v;
      }
}

// ---------------- RoPE in fp32, then split to (hi,lo) bf16; Q pre-scaled by 1/sqrt(128) ----------------
__global__ __launch_bounds__(256) void rope_split(const float* __restrict__ Qf,
                                                  const float* __restrict__ Kf,
                                                  unsigned short* __restrict__ Qh,
                                                  unsigned short* __restrict__ Ql,
                                                  unsigned short* __restrict__ Kh,
                                                  unsigned short* __restrict__ Kl) {
  const int NQ = 2048 * 32 * 64;
  const int NK = 2048 * 8 * 64;
  int idx = blockIdx.x * 256 + threadIdx.x;
  const float* src;
  unsigned short *dh, *dl;
  long base;
  int s, d;
  float scale;
  if (idx < NQ) {
    s = idx >> 11;
    int rem = idx & 2047;
    int hd = rem >> 6; d = rem & 63;
    base = (long)s * 4096 + hd * 128 + d;
    src = Qf; dh = Qh; dl = Ql;
    scale = 0.08838834764831845f;   // 1/sqrt(128)
  } else {
    int k = idx - NQ;
    if (k >= NK) return;
    s = k >> 9;
    int rem = k & 511;
    int hd = rem >> 6; d = rem & 63;
    base = (long)s * 1024 + hd * 128 + d;
    src = Kf; dh = Kh; dl = Kl;
    scale = 1.0f;
  }
  float inv = powf(10000.0f, -(float)d * (1.0f / 64.0f));
  float ang = (float)s * inv;
  float c = cosf(ang), sn = sinf(ang);
  float x1 = src[base], x2 = src[base + 64];
  float y1 = (x1 * c - x2 * sn) * scale;
  float y2 = (x2 * c + x1 * sn) * scale;
  unsigned short h1 = f2bf(y1), h2 = f2bf(y2);
  dh[base] = h1;      dl[base] = f2bf(y1 - bf2f(h1));
  dh[base + 64] = h2; dl[base + 64] = f2bf(y2 - bf2f(h2));
}

// ---------------- attention with Quest-style chunked top-8 selection ----------------
// sc: bf16 [16][2048], 16B-block XOR swizzle (conflict-free P reads).
__device__ __forceinline__ int sidx(int r, int tok) {
  return r * 2048 + ((((tok >> 3) ^ (r & 7)) << 3) | (tok & 7));
}

__global__ __launch_bounds__(256) void attn_kernel(const unsigned short* __restrict__ Qh,
                                                   const unsigned short* __restrict__ Ql,
                                                   const unsigned short* __restrict__ Kh,
                                                   const unsigned short* __restrict__ Kl,
                                                   const unsigned short* __restrict__ Vt,
                                                   unsigned short* __restrict__ AO) {
  __shared__ __align__(16) unsigned short sc[16 * 2048];  // 64 KB: scores then P (bf16)
  __shared__ float cmax[16 * 128];                        // fp32 per-row per-chunk max
  __shared__ float Trow[16];                              // 8th-largest chunk max (fp32)
  __shared__ float denomL[16];
  __shared__ int chunk_any[128];

  const int qb = blockIdx.x, h = blockIdx.y;
  const int kvh = h >> 2;
  const int q0 = qb * 16;
  const int tid = threadIdx.x;
  const int w = tid >> 6, l = tid & 63;
  const int lr = l & 15, lg = l >> 4;
  const float NEGINF = -__builtin_inff();

  for (int i = tid; i < 16 * 128; i += 256) cmax[i] = NEGINF;
  __syncthreads();

  // Q fragments (hi/lo, roped + pre-scaled): A-frag, row = lr, k = lg*8 + i
  bf16x8 qfh[4], qfl[4];
  {
    const unsigned short* qph = Qh + (long)(q0 + lr) * 4096 + h * 128 + lg * 8;
    const unsigned short* qpl = Ql + (long)(q0 + lr) * 4096 + h * 128 + lg * 8;
#pragma unroll
    for (int ks = 0; ks < 4; ++ks) {
      qfh[ks] = *(const bf16x8*)(qph + ks * 32);
      qfl[ks] = *(const bf16x8*)(qpl + ks * 32);
    }
  }

  // ---- QK^T (3-term split) into LDS; fp32 chunk max per 16-col tile ----
  const int nct = qb + 1;
  for (int ct = w; ct < nct; ct += 4) {
    f32x4 acc = {0.f, 0.f, 0.f, 0.f};
    const unsigned short* kph = Kh + (long)(ct * 16 + lr) * 1024 + kvh * 128 + lg * 8;
    const unsigned short* kpl = Kl + (long)(ct * 16 + lr) * 1024 + kvh * 128 + lg * 8;
#pragma unroll
    for (int ks = 0; ks < 4; ++ks) {
      bf16x8 kh = *(const bf16x8*)(kph + ks * 32);
      bf16x8 kl = *(const bf16x8*)(kpl + ks * 32);
      acc = __builtin_amdgcn_mfma_f32_16x16x32_bf16(qfh[ks], kh, acc, 0, 0, 0);
      acc = __builtin_amdgcn_mfma_f32_16x16x32_bf16(qfl[ks], kh, acc, 0, 0, 0);
      acc = __builtin_amdgcn_mfma_f32_16x16x32_bf16(qfh[ks], kl, acc, 0, 0, 0);
    }
    const int tok = ct * 16 + lr;
#pragma unroll
    for (int j = 0; j < 4; ++j) {
      const int r = lg * 4 + j;        // D layout: row = (l>>4)*4 + j, col = l&15
      float sr; unsigned short sb;
      if (tok <= q0 + r) { sr = acc[j]; sb = f2bf(sr); }
      else               { sr = NEGINF; sb = 0xFF80u; }
      float m = sr;
#pragma unroll
      for (int o = 1; o < 16; o <<= 1) m = fmaxf(m, __shfl_xor(m, o));
      sc[sidx(r, tok)] = sb;
      if (lr == 0) cmax[r * 128 + ct] = m;
    }
  }
  __syncthreads();

  // ---- per-row 8th-largest chunk max (wave w -> rows 4w..4w+3), fp32 exact ----
  for (int rr = 0; rr < 4; ++rr) {
    const int r = w * 4 + rr;
    float v0 = cmax[r * 128 + l * 2], v1 = cmax[r * 128 + l * 2 + 1];
    float T = NEGINF;
    for (int it = 0; it < 8; ++it) {
      float m = fmaxf(v0, v1);
      for (int o = 1; o < 64; o <<= 1) m = fmaxf(m, __shfl_xor(m, o));
      unsigned long long bal = __ballot((v0 == m) || (v1 == m));
      int first = __ffsll(bal) - 1;
      if (l == first) { if (v0 == m) v0 = NEGINF; else v1 = NEGINF; }
      T = m;
    }
    if (l == 0) Trow[r] = T;
  }
  __syncthreads();

  // ---- mask + softmax (P stored bf16 in sc) ----
  const int r2 = tid >> 4, i2 = tid & 15;
  const int q = q0 + r2;
  const int n_tok = nct * 16;
  const int ntok32 = ((qb + 2) & ~1) * 16;   // chunks rounded up to even (32-tok k-steps)
  const float Tr = Trow[r2];
  float mx = NEGINF;
  for (int tok = i2; tok < n_tok; tok += 16) {
    float s = bf2f(sc[sidx(r2, tok)]);
    bool al = (s > -1e38f) && ((tok < 128) || (tok > q - 128) || (cmax[r2 * 128 + (tok >> 4)] >= Tr));
    if (al) mx = fmaxf(mx, s);
  }
#pragma unroll
  for (int o = 1; o < 16; o <<= 1) mx = fmaxf(mx, __shfl_xor(mx, o));
  float sum = 0.f;
  for (int tok = i2; tok < ntok32; tok += 16) {
    float p = 0.f;
    if (tok < n_tok) {
      float s = bf2f(sc[sidx(r2, tok)]);
      bool al = (s > -1e38f) && ((tok < 128) || (tok > q - 128) || (cmax[r2 * 128 + (tok >> 4)] >= Tr));
      p = al ? __expf(s - mx) : 0.f;
    }
    unsigned short pb = f2bf(p);
    sc[sidx(r2, tok)] = pb;
    sum += bf2f(pb);
  }
#pragma unroll
  for (int o = 1; o < 16; o <<= 1) sum += __shfl_xor(sum, o);
  if (i2 == 0) denomL[r2] = sum;

  if (tid < 128) {  // chunk-skip hint for PV
    const int c = tid;
    int any = 0;
    for (int r = 0; r < 16; ++r) {
      const int qr = q0 + r;
      if (c * 16 <= qr && ((c < 8) || (c * 16 + 15 > qr - 128) || (cmax[r * 128 + c] >= Trow[r]))) { any = 1; break; }
    }
    chunk_any[c] = any;
  }
  __syncthreads();

  // ---- PV: O[16][128] = P[16][S] * V[S][128]; wave w -> dims [w*32, w*32+32) ----
  f32x4 pacc[2] = {};
  const int d0 = w * 32;
  const int ksmax = ntok32 >> 5;
  for (int ks = 0; ks < ksmax; ++ks) {
    if ((chunk_any[2 * ks] | chunk_any[2 * ks + 1]) == 0) continue;
    const int tokb = ks * 32 + lg * 8;
    bf16x8 pa = *(const bf16x8*)&sc[sidx(lr, tokb)];
#pragma unroll
    for (int sub = 0; sub < 2; ++sub) {
      const unsigned short* vp = Vt + (long)(kvh * 128 + d0 + sub * 16 + lr) * 2048 + tokb;
      bf16x8 vf = *(const bf16x8*)vp;
      pacc[sub] = __builtin_amdgcn_mfma_f32_16x16x32_bf16(pa, vf, pacc[sub], 0, 0, 0);
    }
  }
#pragma unroll
  for (int j = 0; j < 4; ++j) {
    const int r = lg * 4 + j;
    const float rd = 1.0f / denomL[r];
#pragma unroll
    for (int sub = 0; sub < 2; ++sub)
      AO[(long)(q0 + r) * 4096 + h * 128 + d0 + sub * 16 + lr] = f2bf(pacc[sub][j] * rd);
  }
}

// ---------------- launch ----------------
extern "C" void kernel_launch(void* const* d_in, const int* in_sizes, int n_in,
                              void* d_out, int out_size, void* d_ws, size_t ws_size,
                              hipStream_t stream) {
  const float* hidden = (const float*)d_in[0];
  const float* wq = (const float*)d_in[1];
  const float* wk = (const float*)d_in[2];
  const float* wv = (const float*)d_in[3];
  const float* wo = (const float*)d_in[4];
  float* out = (float*)d_out;

  unsigned short* hb_hi = (unsigned short*)d_ws;          // [2048][4096]
  unsigned short* hb_lo = hb_hi + (size_t)2048 * 4096;
  unsigned short* wq_hi = hb_lo + (size_t)2048 * 4096;    // [4096][4096]
  unsigned short* wq_lo = wq_hi + (size_t)4096 * 4096;
  unsigned short* wk_hi = wq_lo + (size_t)4096 * 4096;    // [1024][4096]
  unsigned short* wk_lo = wk_hi + (size_t)1024 * 4096;
  unsigned short* wv_b  = wk_lo + (size_t)1024 * 4096;    // [1024][4096]
  unsigned short* wo_b  = wv_b  + (size_t)1024 * 4096;    // [4096][4096]
  float* Qf = (float*)(wo_b + (size_t)4096 * 4096);       // [2048][4096] fp32
  float* Kf = Qf + (size_t)2048 * 4096;                   // [2048][1024] fp32
  unsigned short* Vt = (unsigned short*)(Kf + (size_t)2048 * 1024);  // [1024][2048] bf16 (dim, tok)
  // aliases (stream-ordered lifetimes):
  unsigned short* Qhi = wq_hi;   // wq splits dead after Q-proj GEMMs
  unsigned short* Qlo = wq_lo;
  unsigned short* Khi = wk_hi;   // wk splits dead after K-proj GEMMs
  unsigned short* Klo = wk_lo;
  unsigned short* AO  = hb_hi;   // hidden splits dead after V GEMM

  cvt_split<<<8192, 256, 0, stream>>>(hidden, hb_hi, hb_lo, 2097152);
  cvt_split<<<16384, 256, 0, stream>>>(wq, wq_hi, wq_lo, 4194304);
  cvt_split<<<4096, 256, 0, stream>>>(wk, wk_hi, wk_lo, 1048576);
  cvt_bf16<<<4096, 256, 0, stream>>>(wv, wv_b, 1048576);
  cvt_bf16<<<16384, 256, 0, stream>>>(wo, wo_b, 4194304);

  // Q = h*wq^T in 3 split passes -> fp32
  gemm_bt<2><<<dim3(32, 16), 256, 0, stream>>>(hb_hi, wq_hi, Qf, 2048, 4096, 4096);
  gemm_bt<3><<<dim3(32, 16), 256, 0, stream>>>(hb_lo, wq_hi, Qf, 2048, 4096, 4096);
  gemm_bt<3><<<dim3(32, 16), 256, 0, stream>>>(hb_hi, wq_lo, Qf, 2048, 4096, 4096);
  // K = h*wk^T in 3 split passes -> fp32
  gemm_bt<2><<<dim3(8, 16), 256, 0, stream>>>(hb_hi, wk_hi, Kf, 2048, 1024, 4096);
  gemm_bt<3><<<dim3(8, 16), 256, 0, stream>>>(hb_lo, wk_hi, Kf, 2048, 1024, 4096);
  gemm_bt<3><<<dim3(8, 16), 256, 0, stream>>>(hb_hi, wk_lo, Kf, 2048, 1024, 4096);
  // V (bf16 path), stored transposed [dim][tok]
  gemm_bt<1><<<dim3(8, 16), 256, 0, stream>>>(hb_hi, wv_b, Vt, 2048, 1024, 4096);

  rope_split<<<20480, 256, 0, stream>>>(Qf, Kf, Qhi, Qlo, Khi, Klo);

  attn_kernel<<<dim3(128, 32), 256, 0, stream>>>(Qhi, Qlo, Khi, Klo, Vt, AO);

  gemm_bt<2><<<dim3(32, 16), 256, 0, stream>>>(AO, wo_b, out, 2048, 4096, 4096);
}

// Round 3
// 941.641 us; speedup vs baseline: 1.8179x; 1.8179x over previous
//
#include <hip/hip_runtime.h>
#include <math.h>

typedef __attribute__((ext_vector_type(4))) float f32x4;
typedef __attribute__((ext_vector_type(8))) __bf16 bf16x8;
typedef __attribute__((ext_vector_type(4))) unsigned short us4;

__device__ __forceinline__ unsigned short f2bf(float f) {
  unsigned int u = __float_as_uint(f);
  u += 0x7fffu + ((u >> 16) & 1u);            // RNE
  return (unsigned short)(u >> 16);
}
__device__ __forceinline__ float bf2f(unsigned short h) {
  return __uint_as_float(((unsigned int)h) << 16);
}

__device__ __forceinline__ void gload16(const void* g, void* l) {
  __builtin_amdgcn_global_load_lds(
      (__attribute__((address_space(1))) void*)g,
      (__attribute__((address_space(3))) void*)l, 16, 0, 0);
}

// ---------------- fp32 -> bf16 convert (plain) ----------------
__global__ __launch_bounds__(256) void cvt_bf16(const float* __restrict__ in,
                                                unsigned short* __restrict__ out, int n4) {
  int i = blockIdx.x * 256 + threadIdx.x;
  if (i < n4) {
    float4 v = ((const float4*)in)[i];
    us4 o;
    o[0] = f2bf(v.x); o[1] = f2bf(v.y); o[2] = f2bf(v.z); o[3] = f2bf(v.w);
    ((us4*)out)[i] = o;
  }
}

// ---------------- fp32 -> (hi, lo) bf16 split ----------------
__global__ __launch_bounds__(256) void cvt_split(const float* __restrict__ in,
                                                 unsigned short* __restrict__ hi,
                                                 unsigned short* __restrict__ lo, int n4) {
  int i = blockIdx.x * 256 + threadIdx.x;
  if (i < n4) {
    float4 v = ((const float4*)in)[i];
    us4 h, l;
    float vv[4] = {v.x, v.y, v.z, v.w};
#pragma unroll
    for (int j = 0; j < 4; ++j) {
      unsigned short hh = f2bf(vv[j]);
      h[j] = hh;
      l[j] = f2bf(vv[j] - bf2f(hh));
    }
    ((us4*)hi)[i] = h;
    ((us4*)lo)[i] = l;
  }
}

// ---------------- GEMM: C = A * B^T (bf16 in, fp32 acc) ----------------
// SM=2: fp32 row-major store. SM=4: bf16 V2 fragment-major store (N=1024 layout).
template<int SM>
__global__ __launch_bounds__(256) void gemm_bt(const unsigned short* __restrict__ A,
                                               const unsigned short* __restrict__ B,
                                               void* __restrict__ C,
                                               int M, int N, int K) {
  __shared__ __align__(16) unsigned short As[128 * 32];
  __shared__ __align__(16) unsigned short Bs[128 * 32];
  const int tid = threadIdx.x;
  const int w = tid >> 6, l = tid & 63;
  const int wm = w >> 1, wn = w & 1;
  const int lr = l & 15, lg = l >> 4;
  const long m0 = (long)blockIdx.y * 128, n0 = (long)blockIdx.x * 128;

  f32x4 acc[4][4] = {};

  const int c0 = w * 128 + l;
  const int c1 = c0 + 64;
  const unsigned short* gA0 = A + (m0 + (c0 >> 2)) * K + (c0 & 3) * 8;
  const unsigned short* gA1 = A + (m0 + (c1 >> 2)) * K + (c1 & 3) * 8;
  const unsigned short* gB0 = B + (n0 + (c0 >> 2)) * K + (c0 & 3) * 8;
  const unsigned short* gB1 = B + (n0 + (c1 >> 2)) * K + (c1 & 3) * 8;

  for (int kt = 0; kt < K; kt += 32) {
    gload16(gA0 + kt, &As[(w * 128) * 8]);
    gload16(gA1 + kt, &As[(w * 128 + 64) * 8]);
    gload16(gB0 + kt, &Bs[(w * 128) * 8]);
    gload16(gB1 + kt, &Bs[(w * 128 + 64) * 8]);
    __syncthreads();
    bf16x8 af[4], bfr[4];
#pragma unroll
    for (int mi = 0; mi < 4; ++mi)
      af[mi] = *(const bf16x8*)&As[(wm * 64 + mi * 16 + lr) * 32 + lg * 8];
#pragma unroll
    for (int ni = 0; ni < 4; ++ni)
      bfr[ni] = *(const bf16x8*)&Bs[(wn * 64 + ni * 16 + lr) * 32 + lg * 8];
#pragma unroll
    for (int mi = 0; mi < 4; ++mi)
#pragma unroll
      for (int ni = 0; ni < 4; ++ni)
        acc[mi][ni] = __builtin_amdgcn_mfma_f32_16x16x32_bf16(af[mi], bfr[ni], acc[mi][ni], 0, 0, 0);
    __syncthreads();
  }

#pragma unroll
  for (int mi = 0; mi < 4; ++mi)
#pragma unroll
    for (int ni = 0; ni < 4; ++ni)
#pragma unroll
      for (int j = 0; j < 4; ++j) {
        long r = m0 + wm * 64 + mi * 16 + lg * 4 + j;
        long cc = n0 + wn * 64 + ni * 16 + lr;
        float v = acc[mi][ni][j];
        if (SM == 2) {
          ((float*)C)[r * N + cc] = v;
        } else {  // SM==4: V2 fragment-major: ((kvh*128+c)*8+dblk)*256 + (t>>3)*128 + (d&15)*8 + (t&7)
          int kvh = (int)(cc >> 7), d = (int)(cc & 127);
          int c = (int)(r >> 4), t = (int)(r & 15);
          long idx = ((long)(kvh * 128 + c) * 8 + (d >> 4)) * 256 + ((t >> 3) * 16 + (d & 15)) * 8 + (t & 7);
          ((unsigned short*)C)[idx] = f2bf(v);
        }
      }
}

// ---------------- fused split GEMM: C = Ah*Bh^T + Al*Bh^T + Ah*Bl^T (fp32 out) ----------------
__global__ __launch_bounds__(256) void gemm_bt3(const unsigned short* __restrict__ Ah,
                                                const unsigned short* __restrict__ Al,
                                                const unsigned short* __restrict__ Bh,
                                                const unsigned short* __restrict__ Bl,
                                                float* __restrict__ C,
                                                int M, int N, int K) {
  __shared__ __align__(16) unsigned short Ash[128 * 32];
  __shared__ __align__(16) unsigned short Asl[128 * 32];
  __shared__ __align__(16) unsigned short Bsh[128 * 32];
  __shared__ __align__(16) unsigned short Bsl[128 * 32];
  const int tid = threadIdx.x;
  const int w = tid >> 6, l = tid & 63;
  const int wm = w >> 1, wn = w & 1;
  const int lr = l & 15, lg = l >> 4;
  const long m0 = (long)blockIdx.y * 128, n0 = (long)blockIdx.x * 128;

  f32x4 acc[4][4] = {};

  const int c0 = w * 128 + l;
  const int c1 = c0 + 64;
  const long oA0 = (m0 + (c0 >> 2)) * K + (c0 & 3) * 8;
  const long oA1 = (m0 + (c1 >> 2)) * K + (c1 & 3) * 8;
  const long oB0 = (n0 + (c0 >> 2)) * K + (c0 & 3) * 8;
  const long oB1 = (n0 + (c1 >> 2)) * K + (c1 & 3) * 8;

  for (int kt = 0; kt < K; kt += 32) {
    gload16(Ah + oA0 + kt, &Ash[(w * 128) * 8]);
    gload16(Ah + oA1 + kt, &Ash[(w * 128 + 64) * 8]);
    gload16(Al + oA0 + kt, &Asl[(w * 128) * 8]);
    gload16(Al + oA1 + kt, &Asl[(w * 128 + 64) * 8]);
    gload16(Bh + oB0 + kt, &Bsh[(w * 128) * 8]);
    gload16(Bh + oB1 + kt, &Bsh[(w * 128 + 64) * 8]);
    gload16(Bl + oB0 + kt, &Bsl[(w * 128) * 8]);
    gload16(Bl + oB1 + kt, &Bsl[(w * 128 + 64) * 8]);
    __syncthreads();
    bf16x8 afh[4], afl[4], bfh[4], bfl[4];
#pragma unroll
    for (int mi = 0; mi < 4; ++mi) {
      afh[mi] = *(const bf16x8*)&Ash[(wm * 64 + mi * 16 + lr) * 32 + lg * 8];
      afl[mi] = *(const bf16x8*)&Asl[(wm * 64 + mi * 16 + lr) * 32 + lg * 8];
    }
#pragma unroll
    for (int ni = 0; ni < 4; ++ni) {
      bfh[ni] = *(const bf16x8*)&Bsh[(wn * 64 + ni * 16 + lr) * 32 + lg * 8];
      bfl[ni] = *(const bf16x8*)&Bsl[(wn * 64 + ni * 16 + lr) * 32 + lg * 8];
    }
#pragma unroll
    for (int mi = 0; mi < 4; ++mi)
#pragma unroll
      for (int ni = 0; ni < 4; ++ni) {
        acc[mi][ni] = __builtin_amdgcn_mfma_f32_16x16x32_bf16(afh[mi], bfh[ni], acc[mi][ni], 0, 0, 0);
        acc[mi][ni] = __builtin_amdgcn_mfma_f32_16x16x32_bf16(afl[mi], bfh[ni], acc[mi][ni], 0, 0, 0);
        acc[mi][ni] = __builtin_amdgcn_mfma_f32_16x16x32_bf16(afh[mi], bfl[ni], acc[mi][ni], 0, 0, 0);
      }
    __syncthreads();
  }

#pragma unroll
  for (int mi = 0; mi < 4; ++mi)
#pragma unroll
    for (int ni = 0; ni < 4; ++ni)
#pragma unroll
      for (int j = 0; j < 4; ++j) {
        long r = m0 + wm * 64 + mi * 16 + lg * 4 + j;
        long cc = n0 + wn * 64 + ni * 16 + lr;
        C[r * N + cc] = acc[mi][ni][j];
      }
}

// ---------------- K2 fragment-major index: K element (s, kvh, d) ----------------
__device__ __forceinline__ long k2idx(int kvh, int s, int d) {
  int ct = s >> 4;
  int lane = (((d & 31) >> 3) << 4) | (s & 15);
  return ((long)(kvh * 128 + ct) * 4 + (d >> 5)) * 512 + lane * 8 + (d & 7);
}

// ---------------- RoPE fp32 -> Q (row-major hi/lo, pre-scaled), K (frag-major hi/lo) ----------------
__global__ __launch_bounds__(256) void rope_split(const float* __restrict__ Qf,
                                                  const float* __restrict__ Kf,
                                                  unsigned short* __restrict__ Qh,
                                                  unsigned short* __restrict__ Ql,
                                                  unsigned short* __restrict__ K2h,
                                                  unsigned short* __restrict__ K2l) {
  const int NQ = 2048 * 32 * 64;
  const int NK = 2048 * 8 * 64;
  int idx = blockIdx.x * 256 + threadIdx.x;
  if (idx < NQ) {
    int s = idx >> 11;
    int rem = idx & 2047;
    int hd = rem >> 6, d = rem & 63;
    long base = (long)s * 4096 + hd * 128 + d;
    float inv = powf(10000.0f, -(float)d * (1.0f / 64.0f));
    float ang = (float)s * inv;
    float c = cosf(ang), sn = sinf(ang);
    float x1 = Qf[base], x2 = Qf[base + 64];
    const float scale = 0.08838834764831845f;  // 1/sqrt(128)
    float y1 = (x1 * c - x2 * sn) * scale;
    float y2 = (x2 * c + x1 * sn) * scale;
    unsigned short h1 = f2bf(y1), h2 = f2bf(y2);
    Qh[base] = h1;      Ql[base] = f2bf(y1 - bf2f(h1));
    Qh[base + 64] = h2; Ql[base + 64] = f2bf(y2 - bf2f(h2));
  } else {
    int k = idx - NQ;
    if (k >= NK) return;
    int s = k >> 9;
    int rem = k & 511;
    int kvh = rem >> 6, d = rem & 63;
    long base = (long)s * 1024 + kvh * 128 + d;
    float inv = powf(10000.0f, -(float)d * (1.0f / 64.0f));
    float ang = (float)s * inv;
    float c = cosf(ang), sn = sinf(ang);
    float x1 = Kf[base], x2 = Kf[base + 64];
    float y1 = x1 * c - x2 * sn;
    float y2 = x2 * c + x1 * sn;
    unsigned short h1 = f2bf(y1), h2 = f2bf(y2);
    long i1 = k2idx(kvh, s, d), i2 = k2idx(kvh, s, d + 64);
    K2h[i1] = h1; K2l[i1] = f2bf(y1 - bf2f(h1));
    K2h[i2] = h2; K2l[i2] = f2bf(y2 - bf2f(h2));
  }
}

// ---------------- P LDS swizzled index: slot, row, tok32 ----------------
__device__ __forceinline__ int pidx(int slot, int r, int t) {
  return slot * 512 + r * 32 + ((((t >> 3) ^ (r & 3)) << 3) | (t & 7));
}

// ---------------- two-phase attention with Quest top-8 chunk selection ----------------
__global__ __launch_bounds__(256) void attn_kernel(const unsigned short* __restrict__ Qh,
                                                   const unsigned short* __restrict__ Ql,
                                                   const unsigned short* __restrict__ K2h,
                                                   const unsigned short* __restrict__ K2l,
                                                   const unsigned short* __restrict__ V2,
                                                   unsigned short* __restrict__ AO) {
  __shared__ float cmax[16 * 128];     // fp32 per-row per-chunk max (exact, split path)
  __shared__ float TrowS[16];          // 8th-largest chunk max
  __shared__ float mxrowS[16];         // softmax normalizer (max over allowed chunks)
  __shared__ float denomP[64];
  __shared__ float dinvS[16];
  __shared__ int clist[128];
  __shared__ int nselS;
  __shared__ __align__(16) unsigned short P[4 * 512];   // 4 pair-slots x [16 rows][32 toks]

  const int qb = (int)gridDim.x - 1 - (int)blockIdx.x;  // heavy blocks first
  const int h = blockIdx.y;
  const int kvh = h >> 2;
  const int q0 = qb * 16;
  const int tid = threadIdx.x;
  const int w = tid >> 6, l = tid & 63;
  const int lr = l & 15, lg = l >> 4;
  const float NEGINF = -__builtin_inff();

  for (int i = tid; i < 16 * 128; i += 256) cmax[i] = NEGINF;

  // Q fragments (hi/lo, roped + pre-scaled): row = lr, k = lg*8 + ks*32 + j
  bf16x8 qfh[4], qfl[4];
  {
    const unsigned short* qph = Qh + (long)(q0 + lr) * 4096 + h * 128 + lg * 8;
    const unsigned short* qpl = Ql + (long)(q0 + lr) * 4096 + h * 128 + lg * 8;
#pragma unroll
    for (int ks = 0; ks < 4; ++ks) {
      qfh[ks] = *(const bf16x8*)(qph + ks * 32);
      qfl[ks] = *(const bf16x8*)(qpl + ks * 32);
    }
  }
  __syncthreads();

  const unsigned short* kbh = K2h + (long)kvh * 128 * 2048;
  const unsigned short* kbl = K2l + (long)kvh * 128 * 2048;

  // ---- phase A: full-precision chunk maxes (scores not stored) ----
  for (int ct = w; ct < qb; ct += 4) {           // full tiles: all tokens causal
    const unsigned short* ph = kbh + (long)ct * 2048 + l * 8;
    const unsigned short* pl = kbl + (long)ct * 2048 + l * 8;
    bf16x8 kh[4], kl2[4];
#pragma unroll
    for (int ks = 0; ks < 4; ++ks) {
      kh[ks] = *(const bf16x8*)(ph + ks * 512);
      kl2[ks] = *(const bf16x8*)(pl + ks * 512);
    }
    f32x4 acc = {};
#pragma unroll
    for (int ks = 0; ks < 4; ++ks) {
      acc = __builtin_amdgcn_mfma_f32_16x16x32_bf16(qfh[ks], kh[ks], acc, 0, 0, 0);
      acc = __builtin_amdgcn_mfma_f32_16x16x32_bf16(qfl[ks], kh[ks], acc, 0, 0, 0);
      acc = __builtin_amdgcn_mfma_f32_16x16x32_bf16(qfh[ks], kl2[ks], acc, 0, 0, 0);
    }
#pragma unroll
    for (int j = 0; j < 4; ++j) {
      float m = acc[j];
#pragma unroll
      for (int o = 1; o < 16; o <<= 1) m = fmaxf(m, __shfl_xor(m, o));
      if (lr == 0) cmax[(lg * 4 + j) * 128 + ct] = m;
    }
  }
  if (w == (qb & 3)) {                            // diagonal tile: causal mask
    const int ct = qb;
    const unsigned short* ph = kbh + (long)ct * 2048 + l * 8;
    const unsigned short* pl = kbl + (long)ct * 2048 + l * 8;
    bf16x8 kh[4], kl2[4];
#pragma unroll
    for (int ks = 0; ks < 4; ++ks) {
      kh[ks] = *(const bf16x8*)(ph + ks * 512);
      kl2[ks] = *(const bf16x8*)(pl + ks * 512);
    }
    f32x4 acc = {};
#pragma unroll
    for (int ks = 0; ks < 4; ++ks) {
      acc = __builtin_amdgcn_mfma_f32_16x16x32_bf16(qfh[ks], kh[ks], acc, 0, 0, 0);
      acc = __builtin_amdgcn_mfma_f32_16x16x32_bf16(qfl[ks], kh[ks], acc, 0, 0, 0);
      acc = __builtin_amdgcn_mfma_f32_16x16x32_bf16(qfh[ks], kl2[ks], acc, 0, 0, 0);
    }
#pragma unroll
    for (int j = 0; j < 4; ++j) {
      const int r = lg * 4 + j;
      float m = (ct * 16 + lr <= q0 + r) ? acc[j] : NEGINF;
#pragma unroll
      for (int o = 1; o < 16; o <<= 1) m = fmaxf(m, __shfl_xor(m, o));
      if (lr == 0) cmax[r * 128 + ct] = m;
    }
  }
  __syncthreads();

  // ---- Trow (8th-largest) + mxrow per row; wave w owns rows 4w..4w+3 ----
  const int nct = qb + 1;
  for (int rr = 0; rr < 4; ++rr) {
    const int r = w * 4 + rr;
    const int qq = q0 + r;
    float v0 = cmax[r * 128 + l * 2], v1 = cmax[r * 128 + l * 2 + 1];
    float T = NEGINF;
    for (int it = 0; it < 8; ++it) {
      float m = fmaxf(v0, v1);
#pragma unroll
      for (int o = 1; o < 64; o <<= 1) m = fmaxf(m, __shfl_xor(m, o));
      unsigned long long bal = __ballot((v0 == m) || (v1 == m));
      int first = __ffsll(bal) - 1;
      if (l == first) { if (v0 == m) v0 = NEGINF; else v1 = NEGINF; }
      T = m;
    }
    float mv = NEGINF;
    for (int c = l; c < nct; c += 64) {
      float cm = cmax[r * 128 + c];
      bool ok = (c < 8) || (c * 16 + 15 > qq - 128) || (cm >= T);
      if (ok) mv = fmaxf(mv, cm);
    }
#pragma unroll
    for (int o = 1; o < 64; o <<= 1) mv = fmaxf(mv, __shfl_xor(mv, o));
    if (l == 0) { TrowS[r] = T; mxrowS[r] = mv; }
  }
  __syncthreads();

  // ---- union chunk list (wave 0, deterministic order) ----
  if (w == 0) {
    int cnt = 0;
    for (int base = 0; base < nct; base += 64) {
      int c = base + l;
      bool ok = false;
      if (c < nct) {
        ok = (c < 8) || (c * 16 + 15 > q0 - 128);
        if (!ok) {
          for (int r = 0; r < 16; ++r)
            if (cmax[r * 128 + c] >= TrowS[r]) { ok = true; break; }
        }
      }
      unsigned long long bal = __ballot(ok);
      if (ok) clist[cnt + __popcll(bal & ((1ull << l) - 1))] = c;
      cnt += __popcll(bal);
    }
    if (l == 0) nselS = cnt;
  }
  __syncthreads();

  const int nsel = nselS;
  const int np = (nsel + 1) >> 1;

  // ---- phase B: recompute selected chunks (bf16 1-term), masked exp, PV ----
  f32x4 pacc[2] = {};
  float psum[4] = {0.f, 0.f, 0.f, 0.f};

  for (int s0 = 0; s0 < np; s0 += 4) {
    const int pi = s0 + w;
    if (pi < np) {
      const int iB = 2 * pi + 1;
      const int cA = clist[2 * pi];
      const int cB = (iB < nsel) ? clist[iB] : cA;
#pragma unroll
      for (int half = 0; half < 2; ++half) {
        const int c = half ? cB : cA;
        const bool vslot = (2 * pi + half) < nsel;
        const unsigned short* ph = kbh + (long)c * 2048 + l * 8;
        f32x4 acc = {};
#pragma unroll
        for (int ks = 0; ks < 4; ++ks) {
          bf16x8 kf = *(const bf16x8*)(ph + ks * 512);
          acc = __builtin_amdgcn_mfma_f32_16x16x32_bf16(qfh[ks], kf, acc, 0, 0, 0);
        }
#pragma unroll
        for (int j = 0; j < 4; ++j) {
          const int r = lg * 4 + j;
          const int qq = q0 + r;
          const int tok = c * 16 + lr;
          bool al = vslot && (tok <= qq) &&
                    ((c < 8) || (tok > qq - 128) || (cmax[r * 128 + c] >= TrowS[r]));
          float p = al ? __expf(acc[j] - mxrowS[r]) : 0.f;
          psum[j] += p;
          P[pidx(w, r, half * 16 + lr)] = f2bf(p);
        }
      }
    }
    __syncthreads();
    const int smax = (np - s0 < 4) ? (np - s0) : 4;
    for (int s = 0; s < smax; ++s) {
      const int p2 = s0 + s;
      const int iB = 2 * p2 + 1;
      const int cA = clist[2 * p2];
      const int cB = (iB < nsel) ? clist[iB] : cA;
      bf16x8 pa = *(const bf16x8*)&P[pidx(s, lr, lg * 8)];
      const int csel = (lg < 2) ? cA : cB;
      const unsigned short* vp = V2 + (long)(kvh * 128 + csel) * 2048 + ((lg & 1) * 16 + lr) * 8;
#pragma unroll
      for (int sub = 0; sub < 2; ++sub) {
        const int dblk = w * 2 + sub;
        bf16x8 vf = *(const bf16x8*)(vp + dblk * 256);
        pacc[sub] = __builtin_amdgcn_mfma_f32_16x16x32_bf16(pa, vf, pacc[sub], 0, 0, 0);
      }
    }
    __syncthreads();
  }

  // ---- denominators ----
#pragma unroll
  for (int j = 0; j < 4; ++j) {
    float ssum = psum[j];
#pragma unroll
    for (int o = 1; o < 16; o <<= 1) ssum += __shfl_xor(ssum, o);
    if (lr == 0) denomP[w * 16 + lg * 4 + j] = ssum;
  }
  __syncthreads();
  if (tid < 16) {
    float dsum = denomP[tid] + denomP[16 + tid] + denomP[32 + tid] + denomP[48 + tid];
    dinvS[tid] = 1.0f / dsum;
  }
  __syncthreads();

#pragma unroll
  for (int j = 0; j < 4; ++j) {
    const int r = lg * 4 + j;
    const float rd = dinvS[r];
#pragma unroll
    for (int sub = 0; sub < 2; ++sub)
      AO[(long)(q0 + r) * 4096 + h * 128 + w * 32 + sub * 16 + lr] = f2bf(pacc[sub][j] * rd);
  }
}

// ---------------- launch ----------------
extern "C" void kernel_launch(void* const* d_in, const int* in_sizes, int n_in,
                              void* d_out, int out_size, void* d_ws, size_t ws_size,
                              hipStream_t stream) {
  const float* hidden = (const float*)d_in[0];
  const float* wq = (const float*)d_in[1];
  const float* wk = (const float*)d_in[2];
  const float* wv = (const float*)d_in[3];
  const float* wo = (const float*)d_in[4];
  float* out = (float*)d_out;

  unsigned short* hb_hi = (unsigned short*)d_ws;          // [2048][4096]
  unsigned short* hb_lo = hb_hi + (size_t)2048 * 4096;
  unsigned short* wq_hi = hb_lo + (size_t)2048 * 4096;    // [4096][4096]
  unsigned short* wq_lo = wq_hi + (size_t)4096 * 4096;
  unsigned short* wk_hi = wq_lo + (size_t)4096 * 4096;    // [1024][4096]
  unsigned short* wk_lo = wk_hi + (size_t)1024 * 4096;
  unsigned short* wv_b  = wk_lo + (size_t)1024 * 4096;    // [1024][4096]
  unsigned short* wo_b  = wv_b  + (size_t)1024 * 4096;    // [4096][4096]
  float* Qf = (float*)(wo_b + (size_t)4096 * 4096);       // [2048][4096] fp32
  float* Kf = Qf + (size_t)2048 * 4096;                   // [2048][1024] fp32
  unsigned short* V2 = (unsigned short*)(Kf + (size_t)2048 * 1024);  // frag-major, 2.1M elems
  // aliases (stream-ordered lifetimes):
  unsigned short* Qhi = wq_hi;   // wq splits dead after Q-proj GEMM
  unsigned short* Qlo = wq_lo;
  unsigned short* K2h = wk_hi;   // wk splits dead after K-proj GEMM
  unsigned short* K2l = wk_lo;
  unsigned short* AO  = hb_hi;   // hidden splits dead after V GEMM

  cvt_split<<<8192, 256, 0, stream>>>(hidden, hb_hi, hb_lo, 2097152);
  cvt_split<<<16384, 256, 0, stream>>>(wq, wq_hi, wq_lo, 4194304);
  cvt_split<<<4096, 256, 0, stream>>>(wk, wk_hi, wk_lo, 1048576);
  cvt_bf16<<<4096, 256, 0, stream>>>(wv, wv_b, 1048576);
  cvt_bf16<<<16384, 256, 0, stream>>>(wo, wo_b, 4194304);

  gemm_bt3<<<dim3(32, 16), 256, 0, stream>>>(hb_hi, hb_lo, wq_hi, wq_lo, Qf, 2048, 4096, 4096);
  gemm_bt3<<<dim3(8, 16), 256, 0, stream>>>(hb_hi, hb_lo, wk_hi, wk_lo, Kf, 2048, 1024, 4096);
  gemm_bt<4><<<dim3(8, 16), 256, 0, stream>>>(hb_hi, wv_b, V2, 2048, 1024, 4096);

  rope_split<<<20480, 256, 0, stream>>>(Qf, Kf, Qhi, Qlo, K2h, K2l);

  attn_kernel<<<dim3(128, 32), 256, 0, stream>>>(Qhi, Qlo, K2h, K2l, V2, AO);

  gemm_bt<2><<<dim3(32, 16), 256, 0, stream>>>(AO, wo_b, out, 2048, 4096, 4096);
}

// Round 4
// 930.507 us; speedup vs baseline: 1.8397x; 1.0120x over previous
//
#include <hip/hip_runtime.h>
#include <math.h>

typedef __attribute__((ext_vector_type(4))) float f32x4;
typedef __attribute__((ext_vector_type(2))) float f32x2;
typedef __attribute__((ext_vector_type(8))) __bf16 bf16x8;
typedef __attribute__((ext_vector_type(4))) unsigned short us4;

__device__ __forceinline__ unsigned short f2bf(float f) {
  unsigned int u = __float_as_uint(f);
  u += 0x7fffu + ((u >> 16) & 1u);            // RNE
  return (unsigned short)(u >> 16);
}
__device__ __forceinline__ float bf2f(unsigned short h) {
  return __uint_as_float(((unsigned int)h) << 16);
}

__device__ __forceinline__ void gload16(const void* g, void* l) {
  __builtin_amdgcn_global_load_lds(
      (__attribute__((address_space(1))) void*)g,
      (__attribute__((address_space(3))) void*)l, 16, 0, 0);
}

// ---------------- fp32 -> bf16 convert (plain) ----------------
__global__ __launch_bounds__(256) void cvt_bf16(const float* __restrict__ in,
                                                unsigned short* __restrict__ out, int n4) {
  int i = blockIdx.x * 256 + threadIdx.x;
  if (i < n4) {
    float4 v = ((const float4*)in)[i];
    us4 o;
    o[0] = f2bf(v.x); o[1] = f2bf(v.y); o[2] = f2bf(v.z); o[3] = f2bf(v.w);
    ((us4*)out)[i] = o;
  }
}

// ---------------- fp32 -> (hi, lo) bf16 split ----------------
__global__ __launch_bounds__(256) void cvt_split(const float* __restrict__ in,
                                                 unsigned short* __restrict__ hi,
                                                 unsigned short* __restrict__ lo, int n4) {
  int i = blockIdx.x * 256 + threadIdx.x;
  if (i < n4) {
    float4 v = ((const float4*)in)[i];
    us4 h, l;
    float vv[4] = {v.x, v.y, v.z, v.w};
#pragma unroll
    for (int j = 0; j < 4; ++j) {
      unsigned short hh = f2bf(vv[j]);
      h[j] = hh;
      l[j] = f2bf(vv[j] - bf2f(hh));
    }
    ((us4*)hi)[i] = h;
    ((us4*)lo)[i] = l;
  }
}

// ---------------- GEMM: C = A * B^T (bf16 in, fp32 acc) ----------------
// SM=2: fp32 row-major store. SM=4: bf16 V2 fragment-major store (N=1024 layout).
template<int SM>
__global__ __launch_bounds__(256) void gemm_bt(const unsigned short* __restrict__ A,
                                               const unsigned short* __restrict__ B,
                                               void* __restrict__ C,
                                               int M, int N, int K) {
  __shared__ __align__(16) unsigned short As[128 * 32];
  __shared__ __align__(16) unsigned short Bs[128 * 32];
  const int tid = threadIdx.x;
  const int w = tid >> 6, l = tid & 63;
  const int wm = w >> 1, wn = w & 1;
  const int lr = l & 15, lg = l >> 4;
  const long m0 = (long)blockIdx.y * 128, n0 = (long)blockIdx.x * 128;

  f32x4 acc[4][4] = {};

  const int c0 = w * 128 + l;
  const int c1 = c0 + 64;
  const unsigned short* gA0 = A + (m0 + (c0 >> 2)) * K + (c0 & 3) * 8;
  const unsigned short* gA1 = A + (m0 + (c1 >> 2)) * K + (c1 & 3) * 8;
  const unsigned short* gB0 = B + (n0 + (c0 >> 2)) * K + (c0 & 3) * 8;
  const unsigned short* gB1 = B + (n0 + (c1 >> 2)) * K + (c1 & 3) * 8;

  for (int kt = 0; kt < K; kt += 32) {
    gload16(gA0 + kt, &As[(w * 128) * 8]);
    gload16(gA1 + kt, &As[(w * 128 + 64) * 8]);
    gload16(gB0 + kt, &Bs[(w * 128) * 8]);
    gload16(gB1 + kt, &Bs[(w * 128 + 64) * 8]);
    __syncthreads();
    bf16x8 af[4], bfr[4];
#pragma unroll
    for (int mi = 0; mi < 4; ++mi)
      af[mi] = *(const bf16x8*)&As[(wm * 64 + mi * 16 + lr) * 32 + lg * 8];
#pragma unroll
    for (int ni = 0; ni < 4; ++ni)
      bfr[ni] = *(const bf16x8*)&Bs[(wn * 64 + ni * 16 + lr) * 32 + lg * 8];
#pragma unroll
    for (int mi = 0; mi < 4; ++mi)
#pragma unroll
      for (int ni = 0; ni < 4; ++ni)
        acc[mi][ni] = __builtin_amdgcn_mfma_f32_16x16x32_bf16(af[mi], bfr[ni], acc[mi][ni], 0, 0, 0);
    __syncthreads();
  }

#pragma unroll
  for (int mi = 0; mi < 4; ++mi)
#pragma unroll
    for (int ni = 0; ni < 4; ++ni)
#pragma unroll
      for (int j = 0; j < 4; ++j) {
        long r = m0 + wm * 64 + mi * 16 + lg * 4 + j;
        long cc = n0 + wn * 64 + ni * 16 + lr;
        float v = acc[mi][ni][j];
        if (SM == 2) {
          ((float*)C)[r * N + cc] = v;
        } else {  // SM==4: V2 fragment-major
          int kvh = (int)(cc >> 7), d = (int)(cc & 127);
          int c = (int)(r >> 4), t = (int)(r & 15);
          long idx = ((long)(kvh * 128 + c) * 8 + (d >> 4)) * 256 + ((t >> 3) * 16 + (d & 15)) * 8 + (t & 7);
          ((unsigned short*)C)[idx] = f2bf(v);
        }
      }
}

// ---------------- fused split GEMM: C = Ah*Bh^T + Al*Bh^T + Ah*Bl^T (fp32 out) ----------------
__global__ __launch_bounds__(256) void gemm_bt3(const unsigned short* __restrict__ Ah,
                                                const unsigned short* __restrict__ Al,
                                                const unsigned short* __restrict__ Bh,
                                                const unsigned short* __restrict__ Bl,
                                                float* __restrict__ C,
                                                int M, int N, int K) {
  __shared__ __align__(16) unsigned short Ash[128 * 32];
  __shared__ __align__(16) unsigned short Asl[128 * 32];
  __shared__ __align__(16) unsigned short Bsh[128 * 32];
  __shared__ __align__(16) unsigned short Bsl[128 * 32];
  const int tid = threadIdx.x;
  const int w = tid >> 6, l = tid & 63;
  const int wm = w >> 1, wn = w & 1;
  const int lr = l & 15, lg = l >> 4;
  const long m0 = (long)blockIdx.y * 128, n0 = (long)blockIdx.x * 128;

  f32x4 acc[4][4] = {};

  const int c0 = w * 128 + l;
  const int c1 = c0 + 64;
  const long oA0 = (m0 + (c0 >> 2)) * K + (c0 & 3) * 8;
  const long oA1 = (m0 + (c1 >> 2)) * K + (c1 & 3) * 8;
  const long oB0 = (n0 + (c0 >> 2)) * K + (c0 & 3) * 8;
  const long oB1 = (n0 + (c1 >> 2)) * K + (c1 & 3) * 8;

  for (int kt = 0; kt < K; kt += 32) {
    gload16(Ah + oA0 + kt, &Ash[(w * 128) * 8]);
    gload16(Ah + oA1 + kt, &Ash[(w * 128 + 64) * 8]);
    gload16(Al + oA0 + kt, &Asl[(w * 128) * 8]);
    gload16(Al + oA1 + kt, &Asl[(w * 128 + 64) * 8]);
    gload16(Bh + oB0 + kt, &Bsh[(w * 128) * 8]);
    gload16(Bh + oB1 + kt, &Bsh[(w * 128 + 64) * 8]);
    gload16(Bl + oB0 + kt, &Bsl[(w * 128) * 8]);
    gload16(Bl + oB1 + kt, &Bsl[(w * 128 + 64) * 8]);
    __syncthreads();
    bf16x8 afh[4], afl[4], bfh[4], bfl[4];
#pragma unroll
    for (int mi = 0; mi < 4; ++mi) {
      afh[mi] = *(const bf16x8*)&Ash[(wm * 64 + mi * 16 + lr) * 32 + lg * 8];
      afl[mi] = *(const bf16x8*)&Asl[(wm * 64 + mi * 16 + lr) * 32 + lg * 8];
    }
#pragma unroll
    for (int ni = 0; ni < 4; ++ni) {
      bfh[ni] = *(const bf16x8*)&Bsh[(wn * 64 + ni * 16 + lr) * 32 + lg * 8];
      bfl[ni] = *(const bf16x8*)&Bsl[(wn * 64 + ni * 16 + lr) * 32 + lg * 8];
    }
#pragma unroll
    for (int mi = 0; mi < 4; ++mi)
#pragma unroll
      for (int ni = 0; ni < 4; ++ni) {
        acc[mi][ni] = __builtin_amdgcn_mfma_f32_16x16x32_bf16(afh[mi], bfh[ni], acc[mi][ni], 0, 0, 0);
        acc[mi][ni] = __builtin_amdgcn_mfma_f32_16x16x32_bf16(afl[mi], bfh[ni], acc[mi][ni], 0, 0, 0);
        acc[mi][ni] = __builtin_amdgcn_mfma_f32_16x16x32_bf16(afh[mi], bfl[ni], acc[mi][ni], 0, 0, 0);
      }
    __syncthreads();
  }

#pragma unroll
  for (int mi = 0; mi < 4; ++mi)
#pragma unroll
    for (int ni = 0; ni < 4; ++ni)
#pragma unroll
      for (int j = 0; j < 4; ++j) {
        long r = m0 + wm * 64 + mi * 16 + lg * 4 + j;
        long cc = n0 + wn * 64 + ni * 16 + lr;
        C[r * N + cc] = acc[mi][ni][j];
      }
}

// ---------------- K2 fragment-major index: K element (s, kvh, d) ----------------
__device__ __forceinline__ long k2idx(int kvh, int s, int d) {
  int ct = s >> 4;
  int lane = (((d & 31) >> 3) << 4) | (s & 15);
  return ((long)(kvh * 128 + ct) * 4 + (d >> 5)) * 512 + lane * 8 + (d & 7);
}

// ---------------- RoPE angle table (bit-identical trig to prior passing rounds) ----------------
__global__ __launch_bounds__(256) void rope_table(float* __restrict__ ctab,
                                                  float* __restrict__ stab) {
  int idx = blockIdx.x * 256 + threadIdx.x;   // 2048*64
  if (idx >= 2048 * 64) return;
  int s = idx >> 6, d = idx & 63;
  float inv = powf(10000.0f, -(float)d * (1.0f / 64.0f));
  float ang = (float)s * inv;
  ctab[idx] = cosf(ang);
  stab[idx] = sinf(ang);
}

// ---------------- RoPE apply: fp32 -> Q (row-major hi/lo, pre-scaled), K (frag-major hi/lo) ----------------
__global__ __launch_bounds__(256) void rope_apply(const float* __restrict__ Qf,
                                                  const float* __restrict__ Kf,
                                                  const float* __restrict__ ctab,
                                                  const float* __restrict__ stab,
                                                  unsigned short* __restrict__ Qh,
                                                  unsigned short* __restrict__ Ql,
                                                  unsigned short* __restrict__ K2h,
                                                  unsigned short* __restrict__ K2l) {
  int t = blockIdx.x * 256 + threadIdx.x;     // 2048*40*16
  if (t >= 2048 * 40 * 16) return;
  int s = t / 640;
  int rem = t - s * 640;
  int hd = rem >> 4;
  int d4 = (rem & 15) * 4;
  float4 cv = *(const float4*)&ctab[s * 64 + d4];
  float4 sv = *(const float4*)&stab[s * 64 + d4];
  float cc[4] = {cv.x, cv.y, cv.z, cv.w};
  float ss[4] = {sv.x, sv.y, sv.z, sv.w};
  us4 h1, l1, h2, l2;
  if (hd < 32) {
    long row = (long)s * 4096 + hd * 128;
    float4 u1 = *(const float4*)&Qf[row + d4];
    float4 u2 = *(const float4*)&Qf[row + 64 + d4];
    float a1[4] = {u1.x, u1.y, u1.z, u1.w};
    float a2[4] = {u2.x, u2.y, u2.z, u2.w};
    const float scale = 0.08838834764831845f;  // 1/sqrt(128)
#pragma unroll
    for (int j = 0; j < 4; ++j) {
      float y1 = (a1[j] * cc[j] - a2[j] * ss[j]) * scale;
      float y2 = (a2[j] * cc[j] + a1[j] * ss[j]) * scale;
      h1[j] = f2bf(y1); l1[j] = f2bf(y1 - bf2f(h1[j]));
      h2[j] = f2bf(y2); l2[j] = f2bf(y2 - bf2f(h2[j]));
    }
    *(us4*)&Qh[row + d4] = h1;      *(us4*)&Ql[row + d4] = l1;
    *(us4*)&Qh[row + 64 + d4] = h2; *(us4*)&Ql[row + 64 + d4] = l2;
  } else {
    int kvh = hd - 32;
    long row = (long)s * 1024 + kvh * 128;
    float4 u1 = *(const float4*)&Kf[row + d4];
    float4 u2 = *(const float4*)&Kf[row + 64 + d4];
    float a1[4] = {u1.x, u1.y, u1.z, u1.w};
    float a2[4] = {u2.x, u2.y, u2.z, u2.w};
#pragma unroll
    for (int j = 0; j < 4; ++j) {
      float y1 = a1[j] * cc[j] - a2[j] * ss[j];
      float y2 = a2[j] * cc[j] + a1[j] * ss[j];
      h1[j] = f2bf(y1); l1[j] = f2bf(y1 - bf2f(h1[j]));
      h2[j] = f2bf(y2); l2[j] = f2bf(y2 - bf2f(h2[j]));
    }
    long i1 = k2idx(kvh, s, d4);
    long i2 = k2idx(kvh, s, d4 + 64);
    *(us4*)&K2h[i1] = h1; *(us4*)&K2l[i1] = l1;
    *(us4*)&K2h[i2] = h2; *(us4*)&K2l[i2] = l2;
  }
}

// ---------------- P LDS swizzled index (per-wave slice): row, tok32 ----------------
__device__ __forceinline__ int pidx2(int r, int t) {
  return r * 32 + ((((t >> 3) ^ (r & 3)) << 3) | (t & 7));
}

// ---------------- GQA-shared two-phase attention, Quest top-8 chunk selection ----------------
// block = (qb, kvh); wave w = q-head kvh*4+w.
__global__ __launch_bounds__(256, 3) void attn_kernel(const unsigned short* __restrict__ Qh,
                                                      const unsigned short* __restrict__ Ql,
                                                      const unsigned short* __restrict__ K2h,
                                                      const unsigned short* __restrict__ K2l,
                                                      const unsigned short* __restrict__ V2,
                                                      unsigned short* __restrict__ AO) {
  __shared__ __align__(16) unsigned short Ksth[2][2048];  // staged K tile hi (double-buffered)
  __shared__ __align__(16) unsigned short Kstl[2][2048];  // staged K tile lo
  __shared__ __align__(16) float cpool[4 * 16 * 128];     // cmax [head][row][chunk]; phase B: P+clist alias

  const int qb = (int)gridDim.x - 1 - (int)blockIdx.x;    // heavy blocks first
  const int kvh = blockIdx.y;
  const int q0 = qb * 16;
  const int nct = qb + 1;
  const int tid = threadIdx.x;
  const int w = tid >> 6, l = tid & 63;
  const int lr = l & 15, lg = l >> 4;
  const int h = kvh * 4 + w;
  const float NEGINF = -__builtin_inff();

  for (int i = tid; i < 4 * 16 * 128; i += 256) cpool[i] = NEGINF;

  // per-wave Q fragments (hi/lo, roped + pre-scaled): row = lr, k = lg*8 + i
  bf16x8 qfh[4], qfl[4];
  {
    const unsigned short* qph = Qh + (long)(q0 + lr) * 4096 + h * 128 + lg * 8;
    const unsigned short* qpl = Ql + (long)(q0 + lr) * 4096 + h * 128 + lg * 8;
#pragma unroll
    for (int ks = 0; ks < 4; ++ks) {
      qfh[ks] = *(const bf16x8*)(qph + ks * 32);
      qfl[ks] = *(const bf16x8*)(qpl + ks * 32);
    }
  }

  const unsigned short* kbh = K2h + (long)kvh * 128 * 2048;
  const unsigned short* kbl = K2l + (long)kvh * 128 * 2048;

  // ---- phase A: exact chunk maxes; K staged via LDS, swapped MFMA (D[tok][qrow]) ----
  {
    gload16(kbh + (w * 64 + l) * 8, &Ksth[0][w * 512]);
    gload16(kbl + (w * 64 + l) * 8, &Kstl[0][w * 512]);
  }
  __syncthreads();

  const int qq = q0 + lr;
  for (int ct = 0; ct < nct; ++ct) {
    const int b = ct & 1;
    if (ct + 1 < nct) {
      gload16(kbh + (long)(ct + 1) * 2048 + (w * 64 + l) * 8, &Ksth[b ^ 1][w * 512]);
      gload16(kbl + (long)(ct + 1) * 2048 + (w * 64 + l) * 8, &Kstl[b ^ 1][w * 512]);
    }
    bf16x8 kh[4], kl2[4];
#pragma unroll
    for (int ks = 0; ks < 4; ++ks) {
      kh[ks]  = *(const bf16x8*)&Ksth[b][l * 8 + ks * 512];
      kl2[ks] = *(const bf16x8*)&Kstl[b][l * 8 + ks * 512];
    }
    f32x4 acc = {};
#pragma unroll
    for (int ks = 0; ks < 4; ++ks) {
      acc = __builtin_amdgcn_mfma_f32_16x16x32_bf16(kh[ks], qfh[ks], acc, 0, 0, 0);
      acc = __builtin_amdgcn_mfma_f32_16x16x32_bf16(kh[ks], qfl[ks], acc, 0, 0, 0);
      acc = __builtin_amdgcn_mfma_f32_16x16x32_bf16(kl2[ks], qfh[ks], acc, 0, 0, 0);
    }
    float m;
    if (ct < qb) {
      m = fmaxf(fmaxf(acc[0], acc[1]), fmaxf(acc[2], acc[3]));
    } else {
      m = NEGINF;
#pragma unroll
      for (int j = 0; j < 4; ++j) {
        int tok = ct * 16 + lg * 4 + j;
        if (tok <= qq) m = fmaxf(m, acc[j]);
      }
    }
    m = fmaxf(m, __shfl_xor(m, 16));
    m = fmaxf(m, __shfl_xor(m, 32));
    if (l < 16) cpool[(w * 16 + l) * 128 + ct] = m;
    asm volatile("s_waitcnt vmcnt(0)" ::: "memory");
    __builtin_amdgcn_sched_barrier(0);
    __builtin_amdgcn_s_barrier();
  }
  __syncthreads();

  // ---- per-row top-8 threshold, normalizer, selection masks (registers via ballot) ----
  float mxj[4];
  unsigned long long selE[4], selO[4];
  unsigned long long uE = 0ull, uO = 0ull;
  const int c0 = 2 * l, c1 = 2 * l + 1;
#pragma unroll 1
  for (int r = 0; r < 16; ++r) {
    f32x2 cv = *(const f32x2*)&cpool[(w * 16 + r) * 128 + 2 * l];
    float v0 = cv[0], v1 = cv[1];
    const float o0 = v0, o1 = v1;
    float T = NEGINF;
    for (int it = 0; it < 8; ++it) {
      float m = fmaxf(v0, v1);
#pragma unroll
      for (int o = 1; o < 64; o <<= 1) m = fmaxf(m, __shfl_xor(m, o));
      unsigned long long bal = __ballot((v0 == m) || (v1 == m));
      int first = __ffsll(bal) - 1;
      if (l == first) { if (v0 == m) v0 = NEGINF; else v1 = NEGINF; }
      T = m;
    }
    bool okc0 = (c0 < 8) || (o0 >= T);          // chunk-level: init | top-8
    bool okc1 = (c1 < 8) || (o1 >= T);
    unsigned long long bE = __ballot(okc0);
    unsigned long long bO = __ballot(okc1);
    uE |= bE; uO |= bO;
    const int qr = q0 + r;
    bool al0 = (c0 < nct) && (okc0 || (c0 * 16 + 15 > qr - 128));
    bool al1 = (c1 < nct) && (okc1 || (c1 * 16 + 15 > qr - 128));
    float mv = fmaxf(al0 ? o0 : NEGINF, al1 ? o1 : NEGINF);
#pragma unroll
    for (int o = 1; o < 64; o <<= 1) mv = fmaxf(mv, __shfl_xor(mv, o));
#pragma unroll
    for (int j = 0; j < 4; ++j) {
      if (r == lg * 4 + j) { mxj[j] = mv; selE[j] = bE; selO[j] = bO; }
    }
  }
  __syncthreads();   // cmax dead; cpool reused as P + clist

  unsigned short* Pw = (unsigned short*)cpool + w * 512;
  int* cl = (int*)((char*)cpool + 4096) + w * 128;

  // ---- per-wave union chunk list (order arbitrary) ----
  bool s0ok = (c0 < nct) && (((uE >> l) & 1ull) || (c0 >= qb - 7));
  bool s1ok = (c1 < nct) && (((uO >> l) & 1ull) || (c1 >= qb - 7));
  unsigned long long bA = __ballot(s0ok);
  unsigned long long bB = __ballot(s1ok);
  const int cntA = __popcll(bA);
  const int nsel = cntA + __popcll(bB);
  if (s0ok) cl[__popcll(bA & ((1ull << l) - 1ull))] = c0;
  if (s1ok) cl[cntA + __popcll(bB & ((1ull << l) - 1ull))] = c1;

  // ---- phase B (per-wave, no block barriers): recompute selected chunks, exp, PV ----
  f32x4 pacc[8] = {};
  float psum[4] = {0.f, 0.f, 0.f, 0.f};
  const int np = (nsel + 1) >> 1;
  for (int pi = 0; pi < np; ++pi) {
    const int cA = cl[2 * pi];
    const int iB = 2 * pi + 1;
    const int cB = (iB < nsel) ? cl[iB] : cA;
#pragma unroll
    for (int half = 0; half < 2; ++half) {
      const int c = half ? cB : cA;
      const bool vslot = (2 * pi + half) < nsel;
      const unsigned short* ph = kbh + (long)c * 2048 + l * 8;
      f32x4 acc = {};
#pragma unroll
      for (int ks = 0; ks < 4; ++ks) {
        bf16x8 kf = *(const bf16x8*)(ph + ks * 512);
        acc = __builtin_amdgcn_mfma_f32_16x16x32_bf16(qfh[ks], kf, acc, 0, 0, 0);
      }
#pragma unroll
      for (int j = 0; j < 4; ++j) {
        const int r = lg * 4 + j;
        const int qrr = q0 + r;
        const int tok = c * 16 + lr;
        unsigned long long sm = (c & 1) ? selO[j] : selE[j];
        bool sel = (sm >> (c >> 1)) & 1ull;
        bool al = vslot && (tok <= qrr) && (sel || (tok > qrr - 128));
        float p = al ? __expf(acc[j] - mxj[j]) : 0.f;
        unsigned short pb = f2bf(p);
        psum[j] += bf2f(pb);
        Pw[pidx2(r, half * 16 + lr)] = pb;
      }
    }
    bf16x8 pa = *(const bf16x8*)&Pw[pidx2(lr, lg * 8)];
    const int csel = (lg < 2) ? cA : cB;
    const unsigned short* vp = V2 + (long)(kvh * 128 + csel) * 2048 + ((lg & 1) * 16 + lr) * 8;
#pragma unroll
    for (int dblk = 0; dblk < 8; ++dblk) {
      bf16x8 vf = *(const bf16x8*)(vp + dblk * 256);
      pacc[dblk] = __builtin_amdgcn_mfma_f32_16x16x32_bf16(pa, vf, pacc[dblk], 0, 0, 0);
    }
  }

  // ---- epilogue: per-row denom (butterfly over lr) + scaled store ----
#pragma unroll
  for (int j = 0; j < 4; ++j) {
    float s = psum[j];
    s += __shfl_xor(s, 1); s += __shfl_xor(s, 2);
    s += __shfl_xor(s, 4); s += __shfl_xor(s, 8);
    const float rd = 1.0f / s;
    const int r = lg * 4 + j;
#pragma unroll
    for (int dblk = 0; dblk < 8; ++dblk)
      AO[(long)(q0 + r) * 4096 + h * 128 + dblk * 16 + lr] = f2bf(pacc[dblk][j] * rd);
  }
}

// ---------------- launch ----------------
extern "C" void kernel_launch(void* const* d_in, const int* in_sizes, int n_in,
                              void* d_out, int out_size, void* d_ws, size_t ws_size,
                              hipStream_t stream) {
  const float* hidden = (const float*)d_in[0];
  const float* wq = (const float*)d_in[1];
  const float* wk = (const float*)d_in[2];
  const float* wv = (const float*)d_in[3];
  const float* wo = (const float*)d_in[4];
  float* out = (float*)d_out;

  unsigned short* hb_hi = (unsigned short*)d_ws;          // [2048][4096]
  unsigned short* hb_lo = hb_hi + (size_t)2048 * 4096;
  unsigned short* wq_hi = hb_lo + (size_t)2048 * 4096;    // [4096][4096]
  unsigned short* wq_lo = wq_hi + (size_t)4096 * 4096;
  unsigned short* wk_hi = wq_lo + (size_t)4096 * 4096;    // [1024][4096]
  unsigned short* wk_lo = wk_hi + (size_t)1024 * 4096;
  unsigned short* wv_b  = wk_lo + (size_t)1024 * 4096;    // [1024][4096]
  unsigned short* wo_b  = wv_b  + (size_t)1024 * 4096;    // [4096][4096]
  float* Qf = (float*)(wo_b + (size_t)4096 * 4096);       // [2048][4096] fp32
  float* Kf = Qf + (size_t)2048 * 4096;                   // [2048][1024] fp32
  unsigned short* V2 = (unsigned short*)(Kf + (size_t)2048 * 1024);  // frag-major, 2.1M elems
  // aliases (stream-ordered lifetimes):
  unsigned short* Qhi = wq_hi;        // wq splits dead after Q-proj GEMM
  unsigned short* Qlo = wq_lo;
  unsigned short* K2h = wk_hi;        // wk splits dead after K-proj GEMM
  unsigned short* K2l = wk_lo;
  unsigned short* AO  = hb_hi;        // hidden splits dead after V GEMM
  float* ctab = (float*)wv_b;         // wv_b dead after V GEMM (1 MB of 8 MB)
  float* stab = ctab + 2048 * 64;

  cvt_split<<<8192, 256, 0, stream>>>(hidden, hb_hi, hb_lo, 2097152);
  cvt_split<<<16384, 256, 0, stream>>>(wq, wq_hi, wq_lo, 4194304);
  cvt_split<<<4096, 256, 0, stream>>>(wk, wk_hi, wk_lo, 1048576);
  cvt_bf16<<<4096, 256, 0, stream>>>(wv, wv_b, 1048576);
  cvt_bf16<<<16384, 256, 0, stream>>>(wo, wo_b, 4194304);

  gemm_bt3<<<dim3(32, 16), 256, 0, stream>>>(hb_hi, hb_lo, wq_hi, wq_lo, Qf, 2048, 4096, 4096);
  gemm_bt3<<<dim3(8, 16), 256, 0, stream>>>(hb_hi, hb_lo, wk_hi, wk_lo, Kf, 2048, 1024, 4096);
  gemm_bt<4><<<dim3(8, 16), 256, 0, stream>>>(hb_hi, wv_b, V2, 2048, 1024, 4096);

  rope_table<<<512, 256, 0, stream>>>(ctab, stab);
  rope_apply<<<5120, 256, 0, stream>>>(Qf, Kf, ctab, stab, Qhi, Qlo, K2h, K2l);

  attn_kernel<<<dim3(128, 8), 256, 0, stream>>>(Qhi, Qlo, K2h, K2l, V2, AO);

  gemm_bt<2><<<dim3(32, 16), 256, 0, stream>>>(AO, wo_b, out, 2048, 4096, 4096);
}